// Round 10
// baseline (466.857 us; speedup 1.0000x reference)
//
#include <hip/hip_runtime.h>
#include <hip/hip_bf16.h>

static inline int cdiv(long long a, long long b) { return (int)((a + b - 1) / b); }

__device__ inline float bf_lo(unsigned u) { return __uint_as_float(u << 16); }
__device__ inline float bf_hi(unsigned u) { return __uint_as_float(u & 0xffff0000u); }

typedef short bf16x8 __attribute__((ext_vector_type(8)));
typedef float f32x4 __attribute__((ext_vector_type(4)));

#define CHUNK 8192

// ---------------- P1 + weight prep fused ----------------

__global__ __launch_bounds__(256) void p1_prep_kernel(
    const int* __restrict__ dst, int* __restrict__ ghist,
    int E, int nchunks, int nb,
    const float* __restrict__ W2rel, const float* __restrict__ W2rt,
    const float* __restrict__ W3rel, const float* __restrict__ W3rt,
    const float* __restrict__ dW1, __hip_bfloat16* __restrict__ wt)
{
    __shared__ int sh[512];
    if (blockIdx.x < (unsigned)nchunks) {
        int c = blockIdx.x;
        for (int i = threadIdx.x; i < nb; i += 256) sh[i] = 0;
        __syncthreads();
        int base = c * CHUNK;
        int end = min(base + CHUNK, E);
        for (int i = base + threadIdx.x; i < end; i += 256)
            atomicAdd(&sh[dst[i] >> 7], 1);
        __syncthreads();
        for (int i = threadIdx.x; i < nb; i += 256)
            ghist[i * nchunks + c] = sh[i];
    } else {
        int i = (blockIdx.x - nchunks) * 256 + threadIdx.x;
        if (i >= 40960) return;
        float v;
        if (i < 8192)       { int n = i >> 7, k = i & 127;               v = W2rel[k * 64 + n]; }
        else if (i < 16384) { int j = i - 8192;  int n = j >> 7, k = j & 127; v = W2rt[k * 64 + n]; }
        else if (i < 20480) { int j = i - 16384; int n = j >> 6, k = j & 63;  v = W3rel[k * 64 + n]; }
        else if (i < 24576) { int j = i - 20480; int n = j >> 6, k = j & 63;  v = W3rt[k * 64 + n]; }
        else if (i < 32768) { int j = i - 24576; int n = j >> 6, k = j & 63;  v = dW1[k * 128 + n]; }
        else                { int j = i - 32768; int n = j >> 6, k = j & 63;  v = dW1[(64 + k) * 128 + n]; }
        wt[i] = __float2bfloat16(v);
    }
}

// ---------------- P2: scatter edges into (bucket,chunk) ranges ----------

__global__ __launch_bounds__(256) void p2_scatter_kernel(
    const int* __restrict__ src, const int* __restrict__ dst,
    const float* __restrict__ ew, const int* __restrict__ gs,
    uint2* __restrict__ bpos, int E, int nchunks, int nb)
{
    __shared__ int cur[512];
    int c = blockIdx.x;
    for (int i = threadIdx.x; i < nb; i += 256) cur[i] = gs[i * nchunks + c];
    __syncthreads();
    int base = c * CHUNK;
    int end = min(base + CHUNK, E);
    for (int i = base + threadIdx.x; i < end; i += 256) {
        int d = dst[i];
        int pos = atomicAdd(&cur[d >> 7], 1);
        bpos[pos] = make_uint2(((unsigned)d << 16) | (unsigned)src[i],
                               __float_as_uint(ew[i]));
    }
}

// ---------------- P3: per-bucket deg/off + place edges (4B csr) ----------

__global__ __launch_bounds__(256) void p3_place_kernel(
    const uint2* __restrict__ bpos, const int* __restrict__ gs,
    int* __restrict__ deg, int* __restrict__ off,
    unsigned* __restrict__ csr4, int E, int nchunks, int nb, int N)
{
    __shared__ int cnt[128];
    __shared__ int pos[128];
    int b = blockIdx.x;
    int nodebase = b << 7;
    if (threadIdx.x < 128) cnt[threadIdx.x] = 0;
    __syncthreads();
    int begin = gs[b * nchunks];
    int bend = (b + 1 < nb) ? gs[(b + 1) * nchunks] : E;
    for (int i = begin + threadIdx.x; i < bend; i += 256)
        atomicAdd(&cnt[(bpos[i].x >> 16) - nodebase], 1);
    __syncthreads();
    int v = 0;
    if (threadIdx.x < 128) { v = cnt[threadIdx.x]; pos[threadIdx.x] = v; }
    __syncthreads();
    #pragma unroll
    for (int ofs = 1; ofs < 128; ofs <<= 1) {
        int t = 0;
        if (threadIdx.x < 128 && threadIdx.x >= ofs) t = pos[threadIdx.x - ofs];
        __syncthreads();
        if (threadIdx.x < 128) pos[threadIdx.x] += t;
        __syncthreads();
    }
    if (threadIdx.x < 128) {
        int ex = begin + pos[threadIdx.x] - v;
        int n = nodebase + threadIdx.x;
        if (n < N) { off[n] = ex; deg[n] = v; }
        cnt[threadIdx.x] = ex;
    }
    __syncthreads();
    for (int i = begin + threadIdx.x; i < bend; i += 256) {
        uint2 en = bpos[i];
        int d = en.x >> 16;
        int p = atomicAdd(&cnt[d - nodebase], 1);
        unsigned u = en.y;
        unsigned wb = (u + 0x7fffu + ((u >> 16) & 1u)) & 0xffff0000u;  // RNE to bf16
        csr4[p] = wb | (en.x & 0xffffu);
    }
}

// ---------------- scan helpers ----------------

__global__ __launch_bounds__(1024) void scan_block_kernel(
    const int* __restrict__ in, int* __restrict__ out,
    int* __restrict__ partials, int N)
{
    __shared__ int sdata[1024];
    const int tid = threadIdx.x;
    const int i = blockIdx.x * 1024 + tid;
    int v = (i < N) ? in[i] : 0;
    sdata[tid] = v;
    __syncthreads();
    #pragma unroll
    for (int ofs = 1; ofs < 1024; ofs <<= 1) {
        int t = (tid >= ofs) ? sdata[tid - ofs] : 0;
        __syncthreads();
        sdata[tid] += t;
        __syncthreads();
    }
    if (i < N) out[i] = sdata[tid] - v;
    if (partials && tid == 1023) partials[blockIdx.x] = sdata[1023];
}

__global__ __launch_bounds__(1024) void scan_add_kernel(
    int* __restrict__ off, const int* __restrict__ blockoff, int N)
{
    int i = blockIdx.x * blockDim.x + threadIdx.x;
    if (i < N) off[i] += blockoff[i >> 10];
}

// ---------------- fused layer 1: CSR gather + expand to 128 (bf16 out) ----

__global__ __launch_bounds__(256) void layer1_fused_kernel(
    const float2* __restrict__ x2, const unsigned* __restrict__ csr4,
    const int* __restrict__ off, const int* __restrict__ deg,
    const float* __restrict__ W1rel, const float* __restrict__ W1rt,
    const float* __restrict__ b1, __hip_bfloat16* __restrict__ h1b, int N)
{
    int t = blockIdx.x * blockDim.x + threadIdx.x;
    int n = t >> 6;
    if (n >= N) return;
    int lane = t & 63;
    int beg = off[n], cnt = deg[n];
    float a0 = 0.f, a1 = 0.f;
    for (int i = lane; i < cnt; i += 64) {
        unsigned c = csr4[beg + i];
        float w = bf_hi(c);
        float2 xs = x2[c & 0xffffu];
        a0 = fmaf(w, xs.x, a0);
        a1 = fmaf(w, xs.y, a1);
    }
    #pragma unroll
    for (int o = 32; o > 0; o >>= 1) {
        a0 += __shfl_xor(a0, o, 64);
        a1 += __shfl_xor(a1, o, 64);
    }
    float2 xn = x2[n];
    float v0 = b1[lane] + a0 * W1rel[lane] + a1 * W1rel[128 + lane]
             + xn.x * W1rt[lane] + xn.y * W1rt[128 + lane];
    float v1 = b1[64 + lane] + a0 * W1rel[64 + lane] + a1 * W1rel[192 + lane]
             + xn.x * W1rt[64 + lane] + xn.y * W1rt[192 + lane];
    h1b[(size_t)n * 128 + lane]      = __float2bfloat16(fmaxf(v0, 0.f));
    h1b[(size_t)n * 128 + 64 + lane] = __float2bfloat16(fmaxf(v1, 0.f));
}

// ---------------- MFMA rel GEMM: out = A @ Wt^T, bf16 out ----------------

template <int K, int NOUT>
__global__ __launch_bounds__(256) void mfma_gemm_kernel(
    const __hip_bfloat16* __restrict__ A,
    const __hip_bfloat16* __restrict__ Wt,
    __hip_bfloat16* __restrict__ outb, int M)
{
    constexpr int KF = K / 32;
    constexpr int SPW = NOUT / 64;
    const int wv = threadIdx.x >> 6;
    const int lane = threadIdx.x & 63;
    const int m = lane & 15, q = lane >> 4;
    const int row0 = blockIdx.x * 16;
    const int arow = row0 + m;

    bf16x8 af[KF];
    #pragma unroll
    for (int kf = 0; kf < KF; kf++)
        af[kf] = *(const bf16x8*)(A + (size_t)arow * K + kf * 32 + q * 8);

    #pragma unroll
    for (int s = 0; s < SPW; s++) {
        const int col = (wv * SPW + s) * 16 + m;
        f32x4 acc = {0.f, 0.f, 0.f, 0.f};
        #pragma unroll
        for (int kf = 0; kf < KF; kf++) {
            bf16x8 bf = *(const bf16x8*)(Wt + (size_t)col * K + kf * 32 + q * 8);
            acc = __builtin_amdgcn_mfma_f32_16x16x32_bf16(af[kf], bf, acc, 0, 0, 0);
        }
        #pragma unroll
        for (int r = 0; r < 4; r++) {
            int rr = row0 + q * 4 + r;
            outb[(size_t)rr * NOUT + col] = __float2bfloat16(acc[r]);
        }
    }
}

// ---------------- fused gather + root MFMA GEMM (interleaved gather) -----
// phase 1: wave gathers its 4 nodes INTERLEAVED (up to 8 edge-loads in
// flight/iteration) into LDS agg[16][64].  phase 2: MFMA + epilogue.

template <int K, int EPI>
__global__ __launch_bounds__(256) void mfma_root_kernel(
    const __hip_bfloat16* __restrict__ A,
    const __hip_bfloat16* __restrict__ Wt,
    const float* __restrict__ bias,
    const unsigned* __restrict__ csr4, const int* __restrict__ off,
    const int* __restrict__ deg,
    const __hip_bfloat162* __restrict__ p,
    __hip_bfloat16* __restrict__ outb, float* __restrict__ outf, int M)
{
    __shared__ float aggL[16][64];
    constexpr int KF = K / 32;
    const int wv = threadIdx.x >> 6;
    const int lane = threadIdx.x & 63;
    const int half = lane >> 5, fp = lane & 31;
    const int row0 = blockIdx.x * 16;
    const int m = lane & 15, q = lane >> 4;

    // pre-issue A fragments (overlaps with gather latency)
    const int arow = row0 + m;
    bf16x8 af[KF];
    #pragma unroll
    for (int kf = 0; kf < KF; kf++)
        af[kf] = *(const bf16x8*)(A + (size_t)arow * K + kf * 32 + q * 8);

    // phase 1: interleaved 4-node gather; half-waves split edges by parity
    int beg[4], cnt[4];
    #pragma unroll
    for (int nn = 0; nn < 4; nn++) {
        int n = row0 + wv * 4 + nn;
        beg[nn] = off[n];
        cnt[nn] = deg[n];
    }
    float a0[4] = {0.f, 0.f, 0.f, 0.f};
    float a1[4] = {0.f, 0.f, 0.f, 0.f};
    int mx = max(max(cnt[0], cnt[1]), max(cnt[2], cnt[3]));
    for (int i = half; i < mx; i += 4) {
        #pragma unroll
        for (int nn = 0; nn < 4; nn++) {
            if (i < cnt[nn]) {
                unsigned c = csr4[beg[nn] + i];
                float2 v = __bfloat1622float2(p[(size_t)(c & 0xffffu) * 32 + fp]);
                float w = bf_hi(c);
                a0[nn] = fmaf(w, v.x, a0[nn]);
                a1[nn] = fmaf(w, v.y, a1[nn]);
            }
        }
        #pragma unroll
        for (int nn = 0; nn < 4; nn++) {
            if (i + 2 < cnt[nn]) {
                unsigned c = csr4[beg[nn] + i + 2];
                float2 v = __bfloat1622float2(p[(size_t)(c & 0xffffu) * 32 + fp]);
                float w = bf_hi(c);
                a0[nn] = fmaf(w, v.x, a0[nn]);
                a1[nn] = fmaf(w, v.y, a1[nn]);
            }
        }
    }
    #pragma unroll
    for (int nn = 0; nn < 4; nn++) {
        float s0 = a0[nn] + __shfl_xor(a0[nn], 32, 64);
        float s1 = a1[nn] + __shfl_xor(a1[nn], 32, 64);
        if (half == 0) {
            aggL[wv * 4 + nn][2 * fp]     = s0;
            aggL[wv * 4 + nn][2 * fp + 1] = s1;
        }
    }
    __syncthreads();

    // phase 2: MFMA (NOUT=64, one 16-col strip per wave)
    const int col = wv * 16 + m;
    f32x4 acc = {0.f, 0.f, 0.f, 0.f};
    #pragma unroll
    for (int kf = 0; kf < KF; kf++) {
        bf16x8 bf = *(const bf16x8*)(Wt + (size_t)col * K + kf * 32 + q * 8);
        acc = __builtin_amdgcn_mfma_f32_16x16x32_bf16(af[kf], bf, acc, 0, 0, 0);
    }
    #pragma unroll
    for (int r = 0; r < 4; r++) {
        int rloc = q * 4 + r;
        size_t idx = (size_t)(row0 + rloc) * 64 + col;
        float v = acc[r] + aggL[rloc][col] + bias[col];
        if (EPI == 1) v = fmaxf(v, 0.f);
        if (EPI == 2) outf[idx] = v;
        outb[idx] = __float2bfloat16(v);
    }
}

// ---------------- dual decoder GEMM ----------------

__global__ __launch_bounds__(256) void dec_gemm_kernel(
    const __hip_bfloat16* __restrict__ A,
    const __hip_bfloat16* __restrict__ Wt0,
    const __hip_bfloat16* __restrict__ Wt1,
    __hip_bfloat16* __restrict__ out0,
    __hip_bfloat16* __restrict__ out1, int gblocks)
{
    constexpr int K = 64, KF = 2, SPW = 2;
    const int hb = (blockIdx.x >= (unsigned)gblocks) ? 1 : 0;
    const __hip_bfloat16* Wt = hb ? Wt1 : Wt0;
    __hip_bfloat16* outb = hb ? out1 : out0;
    const int wv = threadIdx.x >> 6;
    const int lane = threadIdx.x & 63;
    const int m = lane & 15, q = lane >> 4;
    const int row0 = (blockIdx.x - hb * gblocks) * 16;
    const int arow = row0 + m;

    bf16x8 af[KF];
    #pragma unroll
    for (int kf = 0; kf < KF; kf++)
        af[kf] = *(const bf16x8*)(A + (size_t)arow * K + kf * 32 + q * 8);

    #pragma unroll
    for (int s = 0; s < SPW; s++) {
        const int col = (wv * SPW + s) * 16 + m;
        f32x4 acc = {0.f, 0.f, 0.f, 0.f};
        #pragma unroll
        for (int kf = 0; kf < KF; kf++) {
            bf16x8 bf = *(const bf16x8*)(Wt + (size_t)col * K + kf * 32 + q * 8);
            acc = __builtin_amdgcn_mfma_f32_16x16x32_bf16(af[kf], bf, acc, 0, 0, 0);
        }
        #pragma unroll
        for (int r = 0; r < 4; r++) {
            int rr = row0 + q * 4 + r;
            outb[(size_t)rr * 128 + col] = __float2bfloat16(acc[r]);
        }
    }
}

// ---------------- decoder: 16-lane segments, 2 edges in flight -----------

__device__ inline float dec_dot(uint4 ua, uint4 ub,
                                float4 c1a, float4 c1b,
                                float4 w2a, float4 w2b)
{
    float acc;
    acc  = fmaxf(bf_lo(ua.x) + bf_lo(ub.x) + c1a.x, 0.f) * w2a.x;
    acc += fmaxf(bf_hi(ua.x) + bf_hi(ub.x) + c1a.y, 0.f) * w2a.y;
    acc += fmaxf(bf_lo(ua.y) + bf_lo(ub.y) + c1a.z, 0.f) * w2a.z;
    acc += fmaxf(bf_hi(ua.y) + bf_hi(ub.y) + c1a.w, 0.f) * w2a.w;
    acc += fmaxf(bf_lo(ua.z) + bf_lo(ub.z) + c1b.x, 0.f) * w2b.x;
    acc += fmaxf(bf_hi(ua.z) + bf_hi(ub.z) + c1b.y, 0.f) * w2b.y;
    acc += fmaxf(bf_lo(ua.w) + bf_lo(ub.w) + c1b.z, 0.f) * w2b.z;
    acc += fmaxf(bf_hi(ua.w) + bf_hi(ub.w) + c1b.w, 0.f) * w2b.w;
    return acc;
}

__global__ __launch_bounds__(256) void decoder16_kernel(
    const int* __restrict__ src, const int* __restrict__ dst,
    const uint4* __restrict__ Za, const uint4* __restrict__ Zb,
    const float* __restrict__ db1, const float* __restrict__ dW2,
    const float* __restrict__ db2, float* __restrict__ pred,
    int Eobs, int nseg)
{
    int t = blockIdx.x * blockDim.x + threadIdx.x;
    int l = t & 15;
    int seg = t >> 4;
    float4 c1a = ((const float4*)db1)[2 * l];
    float4 c1b = ((const float4*)db1)[2 * l + 1];
    float4 w2a = ((const float4*)dW2)[2 * l];
    float4 w2b = ((const float4*)dW2)[2 * l + 1];
    float b2v = db2[0];

    for (int e = seg; e < Eobs; e += 2 * nseg) {
        int e2 = e + nseg;
        bool has2 = (e2 < Eobs);
        int s = src[e], d = dst[e];
        uint4 ua = Za[(size_t)s * 16 + l];
        uint4 ub = Zb[(size_t)d * 16 + l];
        uint4 ua2, ub2;
        if (has2) {
            int s2 = src[e2], d2 = dst[e2];
            ua2 = Za[(size_t)s2 * 16 + l];
            ub2 = Zb[(size_t)d2 * 16 + l];
        }
        float acc = dec_dot(ua, ub, c1a, c1b, w2a, w2b);
        #pragma unroll
        for (int o = 8; o > 0; o >>= 1) acc += __shfl_xor(acc, o, 64);
        if (l == 0) {
            float pv = acc + b2v;
            pred[e] = pv;
            pred[e + Eobs] = pv;
        }
        if (has2) {
            float acc2 = dec_dot(ua2, ub2, c1a, c1b, w2a, w2b);
            #pragma unroll
            for (int o = 8; o > 0; o >>= 1) acc2 += __shfl_xor(acc2, o, 64);
            if (l == 0) {
                float pv = acc2 + b2v;
                pred[e2] = pv;
                pred[e2 + Eobs] = pv;
            }
        }
    }
}

// ---------------- fallback atomic path kernels ----------------

__global__ __launch_bounds__(256) void scatter_f64_kernel(
    const int* __restrict__ src, const int* __restrict__ dst,
    const float* __restrict__ ew, const float* __restrict__ p,
    float* __restrict__ agg, int E)
{
    int t = blockIdx.x * blockDim.x + threadIdx.x;
    int e = t >> 6;
    if (e >= E) return;
    int j = t & 63;
    atomicAdd(&agg[(size_t)dst[e] * 64 + j], p[(size_t)src[e] * 64 + j] * ew[e]);
}

__global__ __launch_bounds__(256) void scatter_f2_kernel(
    const int* __restrict__ src, const int* __restrict__ dst,
    const float* __restrict__ ew, const float* __restrict__ x,
    float* __restrict__ agg, int E)
{
    int e = blockIdx.x * blockDim.x + threadIdx.x;
    if (e >= E) return;
    int s = src[e], d = dst[e];
    float w = ew[e];
    atomicAdd(&agg[d * 2 + 0], x[s * 2 + 0] * w);
    atomicAdd(&agg[d * 2 + 1], x[s * 2 + 1] * w);
}

__global__ __launch_bounds__(256) void layer1_kernel(
    const float* __restrict__ x, const float* __restrict__ agg,
    const float* __restrict__ W1rel, const float* __restrict__ W1root,
    const float* __restrict__ b1, float* __restrict__ h1, int N)
{
    int t = blockIdx.x * blockDim.x + threadIdx.x;
    if (t >= N * 128) return;
    int n = t >> 7, j = t & 127;
    float v = b1[j]
        + agg[n * 2 + 0] * W1rel[j] + agg[n * 2 + 1] * W1rel[128 + j]
        + x[n * 2 + 0] * W1root[j] + x[n * 2 + 1] * W1root[128 + j];
    h1[t] = fmaxf(v, 0.f);
}

template <int K, int NOUT, bool RELU, bool HAS_EXTRA, bool HAS_BIAS>
__global__ __launch_bounds__(256) void gemm_small(
    const float* __restrict__ in, int M,
    const float* __restrict__ W, int ldw, int woff,
    const float* __restrict__ bias,
    const float* __restrict__ extra,
    float* __restrict__ out)
{
    constexpr int CPT = NOUT / 64;
    __shared__ float sW[K * NOUT];
    __shared__ float sX[4][K];
    const int tid = threadIdx.x;
    const int lane = tid & 63;
    const int wv = tid >> 6;
    for (int idx = tid; idx < K * NOUT; idx += 256) {
        int k = idx / NOUT;
        int j = idx - k * NOUT;
        sW[idx] = W[(size_t)(k + woff) * ldw + j];
    }
    __syncthreads();
    const int ROWS = 32;
    int r0 = blockIdx.x * ROWS;
    for (int rr = wv; rr < ROWS; rr += 4) {
        int r = r0 + rr;
        if (r >= M) break;
        #pragma unroll
        for (int kk = lane; kk < K; kk += 64) sX[wv][kk] = in[(size_t)r * K + kk];
        float acc[CPT][4];
        #pragma unroll
        for (int c = 0; c < CPT; c++)
            #pragma unroll
            for (int u = 0; u < 4; u++) acc[c][u] = 0.f;
        #pragma unroll
        for (int k = 0; k < K; k += 4) {
            #pragma unroll
            for (int u = 0; u < 4; u++) {
                float xv = sX[wv][k + u];
                #pragma unroll
                for (int c = 0; c < CPT; c++)
                    acc[c][u] = fmaf(xv, sW[(k + u) * NOUT + c * 64 + lane], acc[c][u]);
            }
        }
        #pragma unroll
        for (int c = 0; c < CPT; c++) {
            float v = (acc[c][0] + acc[c][1]) + (acc[c][2] + acc[c][3]);
            int j = c * 64 + lane;
            if (HAS_EXTRA) v += extra[(size_t)r * NOUT + j];
            if (HAS_BIAS) v += bias[j];
            if (RELU) v = fmaxf(v, 0.f);
            out[(size_t)r * NOUT + j] = v;
        }
    }
}

__global__ __launch_bounds__(256) void decoder_kernel(
    const int* __restrict__ src, const int* __restrict__ dst,
    const float* __restrict__ Z1a, const float* __restrict__ Z1b,
    const float* __restrict__ db1, const float* __restrict__ dW2,
    const float* __restrict__ db2, float* __restrict__ pred, int Eobs)
{
    int t = blockIdx.x * blockDim.x + threadIdx.x;
    int e = t >> 6;
    if (e >= Eobs) return;
    int lane = threadIdx.x & 63;
    int s = src[e], d = dst[e];
    float t0 = Z1a[(size_t)s * 128 + lane] + Z1b[(size_t)d * 128 + lane] + db1[lane];
    float t1 = Z1a[(size_t)s * 128 + lane + 64] + Z1b[(size_t)d * 128 + lane + 64] + db1[lane + 64];
    t0 = fmaxf(t0, 0.f);
    t1 = fmaxf(t1, 0.f);
    float acc = t0 * dW2[lane] + t1 * dW2[lane + 64];
    #pragma unroll
    for (int off = 32; off > 0; off >>= 1) acc += __shfl_xor(acc, off, 64);
    if (lane == 0) {
        float pv = acc + db2[0];
        pred[e] = pv;
        pred[e + Eobs] = pv;
    }
}

// ---------------- launch ----------------

extern "C" void kernel_launch(void* const* d_in, const int* in_sizes, int n_in,
                              void* d_out, int out_size, void* d_ws, size_t ws_size,
                              hipStream_t stream)
{
    const float* x     = (const float*)d_in[0];
    const int*   ei    = (const int*)d_in[1];
    const float* ew    = (const float*)d_in[2];
    const float* W1rel = (const float*)d_in[4];
    const float* b1    = (const float*)d_in[5];
    const float* W1rt  = (const float*)d_in[6];
    const float* W2rel = (const float*)d_in[7];
    const float* b2    = (const float*)d_in[8];
    const float* W2rt  = (const float*)d_in[9];
    const float* W3rel = (const float*)d_in[10];
    const float* b3    = (const float*)d_in[11];
    const float* W3rt  = (const float*)d_in[12];
    const float* dW1   = (const float*)d_in[13];
    const float* db1   = (const float*)d_in[14];
    const float* dW2   = (const float*)d_in[15];
    const float* db2   = (const float*)d_in[16];

    const int E    = in_sizes[2];
    const int N    = in_sizes[0] / 2;
    const int Eobs = E / 2;
    const int* src = ei;
    const int* dst = ei + E;

    float* R0   = (float*)d_ws;
    float* R1   = R0 + (size_t)N * 64;
    float* R2   = R1 + (size_t)N * 64;
    float* R3   = R2 + (size_t)N * 32;
    float* R4   = R3 + (size_t)N * 32;
    int*   deg  = (int*)(R4 + (size_t)N * 64);
    int*   off  = deg + N;
    int*   par1 = off + N;
    int*   par2 = par1 + 1024;
    float* wtf  = (float*)(par2 + 1024);           // 20480 floats = 40960 bf16
    __hip_bfloat16* wt = (__hip_bfloat16*)wtf;
    unsigned* csr4 = (unsigned*)(wtf + 20480);

    __hip_bfloat16* zb16  = (__hip_bfloat16*)R0;
    __hip_bfloat16* h1b   = (__hip_bfloat16*)R1;
    __hip_bfloat16* Z1a16 = (__hip_bfloat16*)R1;
    __hip_bfloat16* pb16  = (__hip_bfloat16*)R2;
    __hip_bfloat16* h2b   = (__hip_bfloat16*)R3;
    __hip_bfloat16* Z1b16 = (__hip_bfloat16*)R4;
    uint2* bpos  = (uint2*)R4;
    int*   ghist = (int*)R0;

    const int nb      = (N + 127) >> 7;
    const int nchunks = cdiv(E, CHUNK);
    const int M       = nb * nchunks;
    int* ghist_s = ghist + M;

    size_t need = ((size_t)N * 258 + 22528 + (size_t)E * 2) * 4;
    const bool fast = (ws_size >= need) && nb <= 512 && N <= 65535 &&
                      (N % 16 == 0) &&
                      (size_t)E * 2 <= (size_t)N * 64 &&
                      (size_t)M * 2 <= (size_t)N * 64;

    float* pred = (float*)d_out;
    float* z    = pred + E;

    const int nscanM = cdiv(M, 1024);
    const int gblocks = N / 16;

    __hip_bfloat16* wt2rel = wt;
    __hip_bfloat16* wt2rt  = wt + 8192;
    __hip_bfloat16* wt3rel = wt + 16384;
    __hip_bfloat16* wt3rt  = wt + 20480;
    __hip_bfloat16* wtd1a  = wt + 24576;
    __hip_bfloat16* wtd1b  = wt + 32768;

    if (fast) {
        // ---- CSR build + weight prep ----
        p1_prep_kernel<<<nchunks + 160, 256, 0, stream>>>(
            dst, ghist, E, nchunks, nb, W2rel, W2rt, W3rel, W3rt, dW1, wt);
        scan_block_kernel<<<nscanM, 1024, 0, stream>>>(ghist, ghist_s, par1, M);
        scan_block_kernel<<<1, 1024, 0, stream>>>(par1, par2, nullptr, nscanM);
        scan_add_kernel<<<cdiv(M, 1024), 1024, 0, stream>>>(ghist_s, par2, M);
        p2_scatter_kernel<<<nchunks, 256, 0, stream>>>(src, dst, ew, ghist_s, bpos, E, nchunks, nb);
        p3_place_kernel<<<nb, 256, 0, stream>>>(bpos, ghist_s, deg, off, csr4, E, nchunks, nb, N);

        // ---- layer 1 ----
        layer1_fused_kernel<<<cdiv((long long)N * 64, 256), 256, 0, stream>>>(
            (const float2*)x, csr4, off, deg, W1rel, W1rt, b1, h1b, N);

        // ---- layer 2 ----
        mfma_gemm_kernel<128, 64><<<gblocks, 256, 0, stream>>>(h1b, wt2rel, pb16, N);
        mfma_root_kernel<128, 1><<<gblocks, 256, 0, stream>>>(
            h1b, wt2rt, b2, csr4, off, deg, (const __hip_bfloat162*)pb16,
            h2b, nullptr, N);

        // ---- layer 3 ----
        mfma_gemm_kernel<64, 64><<<gblocks, 256, 0, stream>>>(h2b, wt3rel, pb16, N);
        mfma_root_kernel<64, 2><<<gblocks, 256, 0, stream>>>(
            h2b, wt3rt, b3, csr4, off, deg, (const __hip_bfloat162*)pb16,
            zb16, z, N);

        // ---- decoder ----
        dec_gemm_kernel<<<2 * gblocks, 256, 0, stream>>>(
            zb16, wtd1a, wtd1b, Z1a16, Z1b16, gblocks);
        int dblocks = 2048;
        if (dblocks > cdiv((long long)Eobs * 16, 256)) dblocks = cdiv((long long)Eobs * 16, 256);
        int nseg = dblocks * 16;
        decoder16_kernel<<<dblocks, 256, 0, stream>>>(
            src, dst, (const uint4*)Z1a16, (const uint4*)Z1b16,
            db1, dW2, db2, pred, Eobs, nseg);
    } else {
        // ---- fallback: atomic scatter path (fp32 throughout) ----
        float* agg  = R0;
        float* h1   = agg + (size_t)N * 64;
        float* h2   = h1 + (size_t)N * 128;
        float* pbuf = h2 + (size_t)N * 64;
        float* Z1a = h1;
        float* Z1b = h2;
        hipMemsetAsync(agg, 0, (size_t)N * 2 * sizeof(float), stream);
        scatter_f2_kernel<<<cdiv(E, 256), 256, 0, stream>>>(src, dst, ew, x, agg, E);
        layer1_kernel<<<cdiv((long long)N * 128, 256), 256, 0, stream>>>(x, agg, W1rel, W1rt, b1, h1, N);

        gemm_small<128, 64, false, false, false><<<cdiv(N, 32), 256, 0, stream>>>(
            h1, N, W2rel, 64, 0, nullptr, nullptr, pbuf);
        hipMemsetAsync(agg, 0, (size_t)N * 64 * sizeof(float), stream);
        scatter_f64_kernel<<<cdiv((long long)E * 64, 256), 256, 0, stream>>>(src, dst, ew, pbuf, agg, E);
        gemm_small<128, 64, true, true, true><<<cdiv(N, 32), 256, 0, stream>>>(
            h1, N, W2rt, 64, 0, b2, agg, h2);

        gemm_small<64, 64, false, false, false><<<cdiv(N, 32), 256, 0, stream>>>(
            h2, N, W3rel, 64, 0, nullptr, nullptr, pbuf);
        hipMemsetAsync(agg, 0, (size_t)N * 64 * sizeof(float), stream);
        scatter_f64_kernel<<<cdiv((long long)E * 64, 256), 256, 0, stream>>>(src, dst, ew, pbuf, agg, E);
        gemm_small<64, 64, false, true, true><<<cdiv(N, 32), 256, 0, stream>>>(
            h2, N, W3rt, 64, 0, b3, agg, z);

        gemm_small<64, 128, false, false, false><<<cdiv(N, 32), 256, 0, stream>>>(
            z, N, dW1, 128, 0, nullptr, nullptr, Z1a);
        gemm_small<64, 128, false, false, false><<<cdiv(N, 32), 256, 0, stream>>>(
            z, N, dW1, 128, 64, nullptr, nullptr, Z1b);
        decoder_kernel<<<cdiv((long long)Eobs * 64, 256), 256, 0, stream>>>(
            src, dst, Z1a, Z1b, db1, dW2, db2, pred, Eobs);
    }
}

// Round 11
// 361.897 us; speedup vs baseline: 1.2900x; 1.2900x over previous
//
#include <hip/hip_runtime.h>
#include <hip/hip_bf16.h>

static inline int cdiv(long long a, long long b) { return (int)((a + b - 1) / b); }

__device__ inline float bf_lo(unsigned u) { return __uint_as_float(u << 16); }
__device__ inline float bf_hi(unsigned u) { return __uint_as_float(u & 0xffff0000u); }

typedef short bf16x8 __attribute__((ext_vector_type(8)));
typedef float f32x4 __attribute__((ext_vector_type(4)));

#define CHUNK 8192

// ---------------- P1 + weight prep fused ----------------

__global__ __launch_bounds__(256) void p1_prep_kernel(
    const int* __restrict__ dst, int* __restrict__ ghist,
    int E, int nchunks, int nb,
    const float* __restrict__ W2rel, const float* __restrict__ W2rt,
    const float* __restrict__ W3rel, const float* __restrict__ W3rt,
    const float* __restrict__ dW1, __hip_bfloat16* __restrict__ wt)
{
    __shared__ int sh[512];
    if (blockIdx.x < (unsigned)nchunks) {
        int c = blockIdx.x;
        for (int i = threadIdx.x; i < nb; i += 256) sh[i] = 0;
        __syncthreads();
        int base = c * CHUNK;
        int end = min(base + CHUNK, E);
        for (int i = base + threadIdx.x; i < end; i += 256)
            atomicAdd(&sh[dst[i] >> 7], 1);
        __syncthreads();
        for (int i = threadIdx.x; i < nb; i += 256)
            ghist[i * nchunks + c] = sh[i];
    } else {
        int i = (blockIdx.x - nchunks) * 256 + threadIdx.x;
        if (i >= 40960) return;
        float v;
        if (i < 8192)       { int n = i >> 7, k = i & 127;               v = W2rel[k * 64 + n]; }
        else if (i < 16384) { int j = i - 8192;  int n = j >> 7, k = j & 127; v = W2rt[k * 64 + n]; }
        else if (i < 20480) { int j = i - 16384; int n = j >> 6, k = j & 63;  v = W3rel[k * 64 + n]; }
        else if (i < 24576) { int j = i - 20480; int n = j >> 6, k = j & 63;  v = W3rt[k * 64 + n]; }
        else if (i < 32768) { int j = i - 24576; int n = j >> 6, k = j & 63;  v = dW1[k * 128 + n]; }
        else                { int j = i - 32768; int n = j >> 6, k = j & 63;  v = dW1[(64 + k) * 128 + n]; }
        wt[i] = __float2bfloat16(v);
    }
}

// ---------------- P2: scatter edges into (bucket,chunk) ranges ----------

__global__ __launch_bounds__(256) void p2_scatter_kernel(
    const int* __restrict__ src, const int* __restrict__ dst,
    const float* __restrict__ ew, const int* __restrict__ gs,
    uint2* __restrict__ bpos, int E, int nchunks, int nb)
{
    __shared__ int cur[512];
    int c = blockIdx.x;
    for (int i = threadIdx.x; i < nb; i += 256) cur[i] = gs[i * nchunks + c];
    __syncthreads();
    int base = c * CHUNK;
    int end = min(base + CHUNK, E);
    for (int i = base + threadIdx.x; i < end; i += 256) {
        int d = dst[i];
        int pos = atomicAdd(&cur[d >> 7], 1);
        bpos[pos] = make_uint2(((unsigned)d << 16) | (unsigned)src[i],
                               __float_as_uint(ew[i]));
    }
}

// ---------------- P3: per-bucket deg/off + place edges (4B csr) ----------

__global__ __launch_bounds__(256) void p3_place_kernel(
    const uint2* __restrict__ bpos, const int* __restrict__ gs,
    int* __restrict__ deg, int* __restrict__ off,
    unsigned* __restrict__ csr4, int E, int nchunks, int nb, int N)
{
    __shared__ int cnt[128];
    __shared__ int pos[128];
    int b = blockIdx.x;
    int nodebase = b << 7;
    if (threadIdx.x < 128) cnt[threadIdx.x] = 0;
    __syncthreads();
    int begin = gs[b * nchunks];
    int bend = (b + 1 < nb) ? gs[(b + 1) * nchunks] : E;
    for (int i = begin + threadIdx.x; i < bend; i += 256)
        atomicAdd(&cnt[(bpos[i].x >> 16) - nodebase], 1);
    __syncthreads();
    int v = 0;
    if (threadIdx.x < 128) { v = cnt[threadIdx.x]; pos[threadIdx.x] = v; }
    __syncthreads();
    #pragma unroll
    for (int ofs = 1; ofs < 128; ofs <<= 1) {
        int t = 0;
        if (threadIdx.x < 128 && threadIdx.x >= ofs) t = pos[threadIdx.x - ofs];
        __syncthreads();
        if (threadIdx.x < 128) pos[threadIdx.x] += t;
        __syncthreads();
    }
    if (threadIdx.x < 128) {
        int ex = begin + pos[threadIdx.x] - v;
        int n = nodebase + threadIdx.x;
        if (n < N) { off[n] = ex; deg[n] = v; }
        cnt[threadIdx.x] = ex;
    }
    __syncthreads();
    for (int i = begin + threadIdx.x; i < bend; i += 256) {
        uint2 en = bpos[i];
        int d = en.x >> 16;
        int p = atomicAdd(&cnt[d - nodebase], 1);
        unsigned u = en.y;
        unsigned wb = (u + 0x7fffu + ((u >> 16) & 1u)) & 0xffff0000u;  // RNE to bf16
        csr4[p] = wb | (en.x & 0xffffu);
    }
}

// ---------------- scan helpers ----------------

__global__ __launch_bounds__(1024) void scan_block_kernel(
    const int* __restrict__ in, int* __restrict__ out,
    int* __restrict__ partials, int N)
{
    __shared__ int sdata[1024];
    const int tid = threadIdx.x;
    const int i = blockIdx.x * 1024 + tid;
    int v = (i < N) ? in[i] : 0;
    sdata[tid] = v;
    __syncthreads();
    #pragma unroll
    for (int ofs = 1; ofs < 1024; ofs <<= 1) {
        int t = (tid >= ofs) ? sdata[tid - ofs] : 0;
        __syncthreads();
        sdata[tid] += t;
        __syncthreads();
    }
    if (i < N) out[i] = sdata[tid] - v;
    if (partials && tid == 1023) partials[blockIdx.x] = sdata[1023];
}

__global__ __launch_bounds__(1024) void scan_add_kernel(
    int* __restrict__ off, const int* __restrict__ blockoff, int N)
{
    int i = blockIdx.x * blockDim.x + threadIdx.x;
    if (i < N) off[i] += blockoff[i >> 10];
}

// ---------------- fused layer 1: CSR gather + expand to 128 (bf16 out) ----

__global__ __launch_bounds__(256) void layer1_fused_kernel(
    const float2* __restrict__ x2, const unsigned* __restrict__ csr4,
    const int* __restrict__ off, const int* __restrict__ deg,
    const float* __restrict__ W1rel, const float* __restrict__ W1rt,
    const float* __restrict__ b1, __hip_bfloat16* __restrict__ h1b, int N)
{
    int t = blockIdx.x * blockDim.x + threadIdx.x;
    int n = t >> 6;
    if (n >= N) return;
    int lane = t & 63;
    int beg = off[n], cnt = deg[n];
    float a0 = 0.f, a1 = 0.f;
    for (int i = lane; i < cnt; i += 64) {
        unsigned c = csr4[beg + i];
        float w = bf_hi(c);
        float2 xs = x2[c & 0xffffu];
        a0 = fmaf(w, xs.x, a0);
        a1 = fmaf(w, xs.y, a1);
    }
    #pragma unroll
    for (int o = 32; o > 0; o >>= 1) {
        a0 += __shfl_xor(a0, o, 64);
        a1 += __shfl_xor(a1, o, 64);
    }
    float2 xn = x2[n];
    float v0 = b1[lane] + a0 * W1rel[lane] + a1 * W1rel[128 + lane]
             + xn.x * W1rt[lane] + xn.y * W1rt[128 + lane];
    float v1 = b1[64 + lane] + a0 * W1rel[64 + lane] + a1 * W1rel[192 + lane]
             + xn.x * W1rt[64 + lane] + xn.y * W1rt[192 + lane];
    h1b[(size_t)n * 128 + lane]      = __float2bfloat16(fmaxf(v0, 0.f));
    h1b[(size_t)n * 128 + 64 + lane] = __float2bfloat16(fmaxf(v1, 0.f));
}

// ---------------- MFMA rel GEMM: out = A @ Wt^T, bf16 out ----------------

template <int K, int NOUT>
__global__ __launch_bounds__(256) void mfma_gemm_kernel(
    const __hip_bfloat16* __restrict__ A,
    const __hip_bfloat16* __restrict__ Wt,
    __hip_bfloat16* __restrict__ outb, int M)
{
    constexpr int KF = K / 32;
    constexpr int SPW = NOUT / 64;
    const int wv = threadIdx.x >> 6;
    const int lane = threadIdx.x & 63;
    const int m = lane & 15, q = lane >> 4;
    const int row0 = blockIdx.x * 16;
    const int arow = row0 + m;

    bf16x8 af[KF];
    #pragma unroll
    for (int kf = 0; kf < KF; kf++)
        af[kf] = *(const bf16x8*)(A + (size_t)arow * K + kf * 32 + q * 8);

    #pragma unroll
    for (int s = 0; s < SPW; s++) {
        const int col = (wv * SPW + s) * 16 + m;
        f32x4 acc = {0.f, 0.f, 0.f, 0.f};
        #pragma unroll
        for (int kf = 0; kf < KF; kf++) {
            bf16x8 bf = *(const bf16x8*)(Wt + (size_t)col * K + kf * 32 + q * 8);
            acc = __builtin_amdgcn_mfma_f32_16x16x32_bf16(af[kf], bf, acc, 0, 0, 0);
        }
        #pragma unroll
        for (int r = 0; r < 4; r++) {
            int rr = row0 + q * 4 + r;
            outb[(size_t)rr * NOUT + col] = __float2bfloat16(acc[r]);
        }
    }
}

// ---------------- fused gather + root MFMA GEMM ----------------
// phase 1: per-wave sequential 4-node gather; per node, the edge loop is
// 4-slot unrolled UNGUARDED (compiler batches 4 csr loads then 4 p loads
// under one waitcnt each -> 4 loads in flight) with a short guarded tail.
// phase 2: MFMA A@Wt^T; epilogue v = acc + agg + bias (+relu / +fp32 out).

template <int K, int EPI>
__global__ __launch_bounds__(256) void mfma_root_kernel(
    const __hip_bfloat16* __restrict__ A,
    const __hip_bfloat16* __restrict__ Wt,
    const float* __restrict__ bias,
    const unsigned* __restrict__ csr4, const int* __restrict__ off,
    const int* __restrict__ deg,
    const __hip_bfloat162* __restrict__ p,
    __hip_bfloat16* __restrict__ outb, float* __restrict__ outf, int M)
{
    __shared__ float aggL[16][64];
    constexpr int KF = K / 32;
    const int wv = threadIdx.x >> 6;
    const int lane = threadIdx.x & 63;
    const int half = lane >> 5, fp = lane & 31;
    const int row0 = blockIdx.x * 16;
    const int m = lane & 15, q = lane >> 4;

    // pre-issue A fragments (overlaps with gather latency)
    const int arow = row0 + m;
    bf16x8 af[KF];
    #pragma unroll
    for (int kf = 0; kf < KF; kf++)
        af[kf] = *(const bf16x8*)(A + (size_t)arow * K + kf * 32 + q * 8);

    // phase 1: sequential nodes, deep-unrolled edge loop per node
    #pragma unroll
    for (int nn = 0; nn < 4; nn++) {
        int n = row0 + wv * 4 + nn;
        int beg = off[n], cnt = deg[n];
        float a0 = 0.f, a1 = 0.f;
        int i = half;
        for (; i + 6 < cnt; i += 8) {
            unsigned c0 = csr4[beg + i];
            unsigned c1 = csr4[beg + i + 2];
            unsigned c2 = csr4[beg + i + 4];
            unsigned c3 = csr4[beg + i + 6];
            float2 v0 = __bfloat1622float2(p[(size_t)(c0 & 0xffffu) * 32 + fp]);
            float2 v1 = __bfloat1622float2(p[(size_t)(c1 & 0xffffu) * 32 + fp]);
            float2 v2 = __bfloat1622float2(p[(size_t)(c2 & 0xffffu) * 32 + fp]);
            float2 v3 = __bfloat1622float2(p[(size_t)(c3 & 0xffffu) * 32 + fp]);
            float w0 = bf_hi(c0), w1 = bf_hi(c1), w2 = bf_hi(c2), w3 = bf_hi(c3);
            a0 = fmaf(w0, v0.x, a0); a1 = fmaf(w0, v0.y, a1);
            a0 = fmaf(w1, v1.x, a0); a1 = fmaf(w1, v1.y, a1);
            a0 = fmaf(w2, v2.x, a0); a1 = fmaf(w2, v2.y, a1);
            a0 = fmaf(w3, v3.x, a0); a1 = fmaf(w3, v3.y, a1);
        }
        for (; i < cnt; i += 2) {
            unsigned c = csr4[beg + i];
            float2 v = __bfloat1622float2(p[(size_t)(c & 0xffffu) * 32 + fp]);
            float w = bf_hi(c);
            a0 = fmaf(w, v.x, a0); a1 = fmaf(w, v.y, a1);
        }
        a0 += __shfl_xor(a0, 32, 64);
        a1 += __shfl_xor(a1, 32, 64);
        if (half == 0) {
            aggL[wv * 4 + nn][2 * fp]     = a0;
            aggL[wv * 4 + nn][2 * fp + 1] = a1;
        }
    }
    __syncthreads();

    // phase 2: MFMA (NOUT=64, one 16-col strip per wave)
    const int col = wv * 16 + m;
    f32x4 acc = {0.f, 0.f, 0.f, 0.f};
    #pragma unroll
    for (int kf = 0; kf < KF; kf++) {
        bf16x8 bf = *(const bf16x8*)(Wt + (size_t)col * K + kf * 32 + q * 8);
        acc = __builtin_amdgcn_mfma_f32_16x16x32_bf16(af[kf], bf, acc, 0, 0, 0);
    }
    #pragma unroll
    for (int r = 0; r < 4; r++) {
        int rloc = q * 4 + r;
        size_t idx = (size_t)(row0 + rloc) * 64 + col;
        float v = acc[r] + aggL[rloc][col] + bias[col];
        if (EPI == 1) v = fmaxf(v, 0.f);
        if (EPI == 2) outf[idx] = v;
        outb[idx] = __float2bfloat16(v);
    }
}

// ---------------- dual decoder GEMM ----------------

__global__ __launch_bounds__(256) void dec_gemm_kernel(
    const __hip_bfloat16* __restrict__ A,
    const __hip_bfloat16* __restrict__ Wt0,
    const __hip_bfloat16* __restrict__ Wt1,
    __hip_bfloat16* __restrict__ out0,
    __hip_bfloat16* __restrict__ out1, int gblocks)
{
    constexpr int K = 64, KF = 2, SPW = 2;
    const int hb = (blockIdx.x >= (unsigned)gblocks) ? 1 : 0;
    const __hip_bfloat16* Wt = hb ? Wt1 : Wt0;
    __hip_bfloat16* outb = hb ? out1 : out0;
    const int wv = threadIdx.x >> 6;
    const int lane = threadIdx.x & 63;
    const int m = lane & 15, q = lane >> 4;
    const int row0 = (blockIdx.x - hb * gblocks) * 16;
    const int arow = row0 + m;

    bf16x8 af[KF];
    #pragma unroll
    for (int kf = 0; kf < KF; kf++)
        af[kf] = *(const bf16x8*)(A + (size_t)arow * K + kf * 32 + q * 8);

    #pragma unroll
    for (int s = 0; s < SPW; s++) {
        const int col = (wv * SPW + s) * 16 + m;
        f32x4 acc = {0.f, 0.f, 0.f, 0.f};
        #pragma unroll
        for (int kf = 0; kf < KF; kf++) {
            bf16x8 bf = *(const bf16x8*)(Wt + (size_t)col * K + kf * 32 + q * 8);
            acc = __builtin_amdgcn_mfma_f32_16x16x32_bf16(af[kf], bf, acc, 0, 0, 0);
        }
        #pragma unroll
        for (int r = 0; r < 4; r++) {
            int rr = row0 + q * 4 + r;
            outb[(size_t)rr * 128 + col] = __float2bfloat16(acc[r]);
        }
    }
}

// ---------------- decoder: 16-lane segments, 2 edges in flight -----------

__device__ inline float dec_dot(uint4 ua, uint4 ub,
                                float4 c1a, float4 c1b,
                                float4 w2a, float4 w2b)
{
    float acc;
    acc  = fmaxf(bf_lo(ua.x) + bf_lo(ub.x) + c1a.x, 0.f) * w2a.x;
    acc += fmaxf(bf_hi(ua.x) + bf_hi(ub.x) + c1a.y, 0.f) * w2a.y;
    acc += fmaxf(bf_lo(ua.y) + bf_lo(ub.y) + c1a.z, 0.f) * w2a.z;
    acc += fmaxf(bf_hi(ua.y) + bf_hi(ub.y) + c1a.w, 0.f) * w2a.w;
    acc += fmaxf(bf_lo(ua.z) + bf_lo(ub.z) + c1b.x, 0.f) * w2b.x;
    acc += fmaxf(bf_hi(ua.z) + bf_hi(ub.z) + c1b.y, 0.f) * w2b.y;
    acc += fmaxf(bf_lo(ua.w) + bf_lo(ub.w) + c1b.z, 0.f) * w2b.z;
    acc += fmaxf(bf_hi(ua.w) + bf_hi(ub.w) + c1b.w, 0.f) * w2b.w;
    return acc;
}

__global__ __launch_bounds__(256) void decoder16_kernel(
    const int* __restrict__ src, const int* __restrict__ dst,
    const uint4* __restrict__ Za, const uint4* __restrict__ Zb,
    const float* __restrict__ db1, const float* __restrict__ dW2,
    const float* __restrict__ db2, float* __restrict__ pred,
    int Eobs, int nseg)
{
    int t = blockIdx.x * blockDim.x + threadIdx.x;
    int l = t & 15;
    int seg = t >> 4;
    float4 c1a = ((const float4*)db1)[2 * l];
    float4 c1b = ((const float4*)db1)[2 * l + 1];
    float4 w2a = ((const float4*)dW2)[2 * l];
    float4 w2b = ((const float4*)dW2)[2 * l + 1];
    float b2v = db2[0];

    for (int e = seg; e < Eobs; e += 2 * nseg) {
        int e2 = e + nseg;
        bool has2 = (e2 < Eobs);
        int s = src[e], d = dst[e];
        uint4 ua = Za[(size_t)s * 16 + l];
        uint4 ub = Zb[(size_t)d * 16 + l];
        uint4 ua2, ub2;
        if (has2) {
            int s2 = src[e2], d2 = dst[e2];
            ua2 = Za[(size_t)s2 * 16 + l];
            ub2 = Zb[(size_t)d2 * 16 + l];
        }
        float acc = dec_dot(ua, ub, c1a, c1b, w2a, w2b);
        #pragma unroll
        for (int o = 8; o > 0; o >>= 1) acc += __shfl_xor(acc, o, 64);
        if (l == 0) {
            float pv = acc + b2v;
            pred[e] = pv;
            pred[e + Eobs] = pv;
        }
        if (has2) {
            float acc2 = dec_dot(ua2, ub2, c1a, c1b, w2a, w2b);
            #pragma unroll
            for (int o = 8; o > 0; o >>= 1) acc2 += __shfl_xor(acc2, o, 64);
            if (l == 0) {
                float pv = acc2 + b2v;
                pred[e2] = pv;
                pred[e2 + Eobs] = pv;
            }
        }
    }
}

// ---------------- fallback atomic path kernels ----------------

__global__ __launch_bounds__(256) void scatter_f64_kernel(
    const int* __restrict__ src, const int* __restrict__ dst,
    const float* __restrict__ ew, const float* __restrict__ p,
    float* __restrict__ agg, int E)
{
    int t = blockIdx.x * blockDim.x + threadIdx.x;
    int e = t >> 6;
    if (e >= E) return;
    int j = t & 63;
    atomicAdd(&agg[(size_t)dst[e] * 64 + j], p[(size_t)src[e] * 64 + j] * ew[e]);
}

__global__ __launch_bounds__(256) void scatter_f2_kernel(
    const int* __restrict__ src, const int* __restrict__ dst,
    const float* __restrict__ ew, const float* __restrict__ x,
    float* __restrict__ agg, int E)
{
    int e = blockIdx.x * blockDim.x + threadIdx.x;
    if (e >= E) return;
    int s = src[e], d = dst[e];
    float w = ew[e];
    atomicAdd(&agg[d * 2 + 0], x[s * 2 + 0] * w);
    atomicAdd(&agg[d * 2 + 1], x[s * 2 + 1] * w);
}

__global__ __launch_bounds__(256) void layer1_kernel(
    const float* __restrict__ x, const float* __restrict__ agg,
    const float* __restrict__ W1rel, const float* __restrict__ W1root,
    const float* __restrict__ b1, float* __restrict__ h1, int N)
{
    int t = blockIdx.x * blockDim.x + threadIdx.x;
    if (t >= N * 128) return;
    int n = t >> 7, j = t & 127;
    float v = b1[j]
        + agg[n * 2 + 0] * W1rel[j] + agg[n * 2 + 1] * W1rel[128 + j]
        + x[n * 2 + 0] * W1root[j] + x[n * 2 + 1] * W1root[128 + j];
    h1[t] = fmaxf(v, 0.f);
}

template <int K, int NOUT, bool RELU, bool HAS_EXTRA, bool HAS_BIAS>
__global__ __launch_bounds__(256) void gemm_small(
    const float* __restrict__ in, int M,
    const float* __restrict__ W, int ldw, int woff,
    const float* __restrict__ bias,
    const float* __restrict__ extra,
    float* __restrict__ out)
{
    constexpr int CPT = NOUT / 64;
    __shared__ float sW[K * NOUT];
    __shared__ float sX[4][K];
    const int tid = threadIdx.x;
    const int lane = tid & 63;
    const int wv = tid >> 6;
    for (int idx = tid; idx < K * NOUT; idx += 256) {
        int k = idx / NOUT;
        int j = idx - k * NOUT;
        sW[idx] = W[(size_t)(k + woff) * ldw + j];
    }
    __syncthreads();
    const int ROWS = 32;
    int r0 = blockIdx.x * ROWS;
    for (int rr = wv; rr < ROWS; rr += 4) {
        int r = r0 + rr;
        if (r >= M) break;
        #pragma unroll
        for (int kk = lane; kk < K; kk += 64) sX[wv][kk] = in[(size_t)r * K + kk];
        float acc[CPT][4];
        #pragma unroll
        for (int c = 0; c < CPT; c++)
            #pragma unroll
            for (int u = 0; u < 4; u++) acc[c][u] = 0.f;
        #pragma unroll
        for (int k = 0; k < K; k += 4) {
            #pragma unroll
            for (int u = 0; u < 4; u++) {
                float xv = sX[wv][k + u];
                #pragma unroll
                for (int c = 0; c < CPT; c++)
                    acc[c][u] = fmaf(xv, sW[(k + u) * NOUT + c * 64 + lane], acc[c][u]);
            }
        }
        #pragma unroll
        for (int c = 0; c < CPT; c++) {
            float v = (acc[c][0] + acc[c][1]) + (acc[c][2] + acc[c][3]);
            int j = c * 64 + lane;
            if (HAS_EXTRA) v += extra[(size_t)r * NOUT + j];
            if (HAS_BIAS) v += bias[j];
            if (RELU) v = fmaxf(v, 0.f);
            out[(size_t)r * NOUT + j] = v;
        }
    }
}

__global__ __launch_bounds__(256) void decoder_kernel(
    const int* __restrict__ src, const int* __restrict__ dst,
    const float* __restrict__ Z1a, const float* __restrict__ Z1b,
    const float* __restrict__ db1, const float* __restrict__ dW2,
    const float* __restrict__ db2, float* __restrict__ pred, int Eobs)
{
    int t = blockIdx.x * blockDim.x + threadIdx.x;
    int e = t >> 6;
    if (e >= Eobs) return;
    int lane = threadIdx.x & 63;
    int s = src[e], d = dst[e];
    float t0 = Z1a[(size_t)s * 128 + lane] + Z1b[(size_t)d * 128 + lane] + db1[lane];
    float t1 = Z1a[(size_t)s * 128 + lane + 64] + Z1b[(size_t)d * 128 + lane + 64] + db1[lane + 64];
    t0 = fmaxf(t0, 0.f);
    t1 = fmaxf(t1, 0.f);
    float acc = t0 * dW2[lane] + t1 * dW2[lane + 64];
    #pragma unroll
    for (int off = 32; off > 0; off >>= 1) acc += __shfl_xor(acc, off, 64);
    if (lane == 0) {
        float pv = acc + db2[0];
        pred[e] = pv;
        pred[e + Eobs] = pv;
    }
}

// ---------------- launch ----------------

extern "C" void kernel_launch(void* const* d_in, const int* in_sizes, int n_in,
                              void* d_out, int out_size, void* d_ws, size_t ws_size,
                              hipStream_t stream)
{
    const float* x     = (const float*)d_in[0];
    const int*   ei    = (const int*)d_in[1];
    const float* ew    = (const float*)d_in[2];
    const float* W1rel = (const float*)d_in[4];
    const float* b1    = (const float*)d_in[5];
    const float* W1rt  = (const float*)d_in[6];
    const float* W2rel = (const float*)d_in[7];
    const float* b2    = (const float*)d_in[8];
    const float* W2rt  = (const float*)d_in[9];
    const float* W3rel = (const float*)d_in[10];
    const float* b3    = (const float*)d_in[11];
    const float* W3rt  = (const float*)d_in[12];
    const float* dW1   = (const float*)d_in[13];
    const float* db1   = (const float*)d_in[14];
    const float* dW2   = (const float*)d_in[15];
    const float* db2   = (const float*)d_in[16];

    const int E    = in_sizes[2];
    const int N    = in_sizes[0] / 2;
    const int Eobs = E / 2;
    const int* src = ei;
    const int* dst = ei + E;

    float* R0   = (float*)d_ws;
    float* R1   = R0 + (size_t)N * 64;
    float* R2   = R1 + (size_t)N * 64;
    float* R3   = R2 + (size_t)N * 32;
    float* R4   = R3 + (size_t)N * 32;
    int*   deg  = (int*)(R4 + (size_t)N * 64);
    int*   off  = deg + N;
    int*   par1 = off + N;
    int*   par2 = par1 + 1024;
    float* wtf  = (float*)(par2 + 1024);           // 20480 floats = 40960 bf16
    __hip_bfloat16* wt = (__hip_bfloat16*)wtf;
    unsigned* csr4 = (unsigned*)(wtf + 20480);

    __hip_bfloat16* zb16  = (__hip_bfloat16*)R0;
    __hip_bfloat16* h1b   = (__hip_bfloat16*)R1;
    __hip_bfloat16* Z1a16 = (__hip_bfloat16*)R1;
    __hip_bfloat16* pb16  = (__hip_bfloat16*)R2;
    __hip_bfloat16* h2b   = (__hip_bfloat16*)R3;
    __hip_bfloat16* Z1b16 = (__hip_bfloat16*)R4;
    uint2* bpos  = (uint2*)R4;
    int*   ghist = (int*)R0;

    const int nb      = (N + 127) >> 7;
    const int nchunks = cdiv(E, CHUNK);
    const int M       = nb * nchunks;
    int* ghist_s = ghist + M;

    size_t need = ((size_t)N * 258 + 22528 + (size_t)E * 2) * 4;
    const bool fast = (ws_size >= need) && nb <= 512 && N <= 65535 &&
                      (N % 16 == 0) &&
                      (size_t)E * 2 <= (size_t)N * 64 &&
                      (size_t)M * 2 <= (size_t)N * 64;

    float* pred = (float*)d_out;
    float* z    = pred + E;

    const int nscanM = cdiv(M, 1024);
    const int gblocks = N / 16;

    __hip_bfloat16* wt2rel = wt;
    __hip_bfloat16* wt2rt  = wt + 8192;
    __hip_bfloat16* wt3rel = wt + 16384;
    __hip_bfloat16* wt3rt  = wt + 20480;
    __hip_bfloat16* wtd1a  = wt + 24576;
    __hip_bfloat16* wtd1b  = wt + 32768;

    if (fast) {
        // ---- CSR build + weight prep ----
        p1_prep_kernel<<<nchunks + 160, 256, 0, stream>>>(
            dst, ghist, E, nchunks, nb, W2rel, W2rt, W3rel, W3rt, dW1, wt);
        scan_block_kernel<<<nscanM, 1024, 0, stream>>>(ghist, ghist_s, par1, M);
        scan_block_kernel<<<1, 1024, 0, stream>>>(par1, par2, nullptr, nscanM);
        scan_add_kernel<<<cdiv(M, 1024), 1024, 0, stream>>>(ghist_s, par2, M);
        p2_scatter_kernel<<<nchunks, 256, 0, stream>>>(src, dst, ew, ghist_s, bpos, E, nchunks, nb);
        p3_place_kernel<<<nb, 256, 0, stream>>>(bpos, ghist_s, deg, off, csr4, E, nchunks, nb, N);

        // ---- layer 1 ----
        layer1_fused_kernel<<<cdiv((long long)N * 64, 256), 256, 0, stream>>>(
            (const float2*)x, csr4, off, deg, W1rel, W1rt, b1, h1b, N);

        // ---- layer 2 ----
        mfma_gemm_kernel<128, 64><<<gblocks, 256, 0, stream>>>(h1b, wt2rel, pb16, N);
        mfma_root_kernel<128, 1><<<gblocks, 256, 0, stream>>>(
            h1b, wt2rt, b2, csr4, off, deg, (const __hip_bfloat162*)pb16,
            h2b, nullptr, N);

        // ---- layer 3 ----
        mfma_gemm_kernel<64, 64><<<gblocks, 256, 0, stream>>>(h2b, wt3rel, pb16, N);
        mfma_root_kernel<64, 2><<<gblocks, 256, 0, stream>>>(
            h2b, wt3rt, b3, csr4, off, deg, (const __hip_bfloat162*)pb16,
            zb16, z, N);

        // ---- decoder ----
        dec_gemm_kernel<<<2 * gblocks, 256, 0, stream>>>(
            zb16, wtd1a, wtd1b, Z1a16, Z1b16, gblocks);
        int dblocks = 2048;
        if (dblocks > cdiv((long long)Eobs * 16, 256)) dblocks = cdiv((long long)Eobs * 16, 256);
        int nseg = dblocks * 16;
        decoder16_kernel<<<dblocks, 256, 0, stream>>>(
            src, dst, (const uint4*)Z1a16, (const uint4*)Z1b16,
            db1, dW2, db2, pred, Eobs, nseg);
    } else {
        // ---- fallback: atomic scatter path (fp32 throughout) ----
        float* agg  = R0;
        float* h1   = agg + (size_t)N * 64;
        float* h2   = h1 + (size_t)N * 128;
        float* pbuf = h2 + (size_t)N * 64;
        float* Z1a = h1;
        float* Z1b = h2;
        hipMemsetAsync(agg, 0, (size_t)N * 2 * sizeof(float), stream);
        scatter_f2_kernel<<<cdiv(E, 256), 256, 0, stream>>>(src, dst, ew, x, agg, E);
        layer1_kernel<<<cdiv((long long)N * 128, 256), 256, 0, stream>>>(x, agg, W1rel, W1rt, b1, h1, N);

        gemm_small<128, 64, false, false, false><<<cdiv(N, 32), 256, 0, stream>>>(
            h1, N, W2rel, 64, 0, nullptr, nullptr, pbuf);
        hipMemsetAsync(agg, 0, (size_t)N * 64 * sizeof(float), stream);
        scatter_f64_kernel<<<cdiv((long long)E * 64, 256), 256, 0, stream>>>(src, dst, ew, pbuf, agg, E);
        gemm_small<128, 64, true, true, true><<<cdiv(N, 32), 256, 0, stream>>>(
            h1, N, W2rt, 64, 0, b2, agg, h2);

        gemm_small<64, 64, false, false, false><<<cdiv(N, 32), 256, 0, stream>>>(
            h2, N, W3rel, 64, 0, nullptr, nullptr, pbuf);
        hipMemsetAsync(agg, 0, (size_t)N * 64 * sizeof(float), stream);
        scatter_f64_kernel<<<cdiv((long long)E * 64, 256), 256, 0, stream>>>(src, dst, ew, pbuf, agg, E);
        gemm_small<64, 64, false, true, true><<<cdiv(N, 32), 256, 0, stream>>>(
            h2, N, W3rt, 64, 0, b3, agg, z);

        gemm_small<64, 128, false, false, false><<<cdiv(N, 32), 256, 0, stream>>>(
            z, N, dW1, 128, 0, nullptr, nullptr, Z1a);
        gemm_small<64, 128, false, false, false><<<cdiv(N, 32), 256, 0, stream>>>(
            z, N, dW1, 128, 64, nullptr, nullptr, Z1b);
        decoder_kernel<<<cdiv((long long)Eobs * 64, 256), 256, 0, stream>>>(
            src, dst, Z1a, Z1b, db1, dW2, db2, pred, Eobs);
    }
}